// Round 9
// baseline (277.235 us; speedup 1.0000x reference)
//
#include <hip/hip_runtime.h>
#include <stdint.h>

#define WW 48
#define NQ 2304             // 48*48
#define NWT 144             // (bh, qt) tiles of 256 queries
#define SCL 0.51011868f     // 8^-0.5 * log2(e)  (folded so softmax = exp2)
#define SHIFT 17.312340491f // 12 * log2(e)      (fixed-shift softmax)
#define PSLAB 2304          // 9 * 256 floats per (kc, wt) partial slab
#define CTROFF (8 * NWT * PSLAB * 4)   // byte offset of counters in ws (10.6 MB)

__device__ __forceinline__ float rdl(float v, int l) {
    return __int_as_float(__builtin_amdgcn_readlane(__float_as_int(v), l));
}

// ---------------------------------------------------------------------------
// Fused attention. 2 queries/lane, 2-wave blocks, 8-way key split.
// grid 1152 = 16 bh * 9 qt * 8 kc -> 2304 waves = 2.25/SIMD (R8 was 1.1).
// Keys via v_readlane broadcast (zero per-lane KV bytes - R5/R6 walls);
// rel tables staged in LDS; qh batch-computed per 8-row round (R8's exposed
// per-row dependent global relh loads were the 46%-VALUBusy stall).
// logit = q.k + q.rel_w[x2-x+47] + q.rel_h[y2-y+47]; p = exp2(logit'-SHIFT)
// Last kc-block per query-tile (device-scope atomic counter) merges the 8
// partial slabs and writes out — kills the second launch (~50us fixed gap).
// ---------------------------------------------------------------------------
__global__ __launch_bounds__(128, 4) void attn_fused(const float* __restrict__ in,
                                                     const float* __restrict__ relw,
                                                     const float* __restrict__ relh,
                                                     float* __restrict__ P,
                                                     unsigned int* __restrict__ ctr,
                                                     float* __restrict__ out) {
    __shared__ float lrelw[95 * 8];
    __shared__ float lrelh[95 * 8];
    __shared__ int sflag;

    const int bx = blockIdx.x;
    const int bh = bx / 72;
    const int rem = bx - bh * 72;
    const int qt = rem >> 3;           // 0..8
    const int kc = rem & 7;            // 0..7
    const int tid = threadIdx.x;
    const int lane = tid & 63;
    const int wv = tid >> 6;           // 0..1
    const int b = bh >> 3, h = bh & 7;
    const int wt = bh * 9 + qt;

    // ---- stage rel tables into LDS (95 rows x 8 floats each) ----
    for (int i = tid; i < 760; i += 128) {
        lrelw[i] = relw[i];
        lrelh[i] = relh[i];
    }
    __syncthreads();

    // ---- this lane's two queries ----
    const int n0 = qt * 256 + wv * 128 + lane;
    const int n1 = n0 + 64;
    const int y0 = n0 / WW, x0 = n0 - y0 * WW;
    const int y1 = n1 / WW, x1 = n1 - y1 * WW;

    const float* qp0 = in + ((size_t)(b * NQ + n0) * 192 + h * 8);
    const float* qp1 = in + ((size_t)(b * NQ + n1) * 192 + h * 8);
    float4 q0a = *(const float4*)qp0, q0b = *(const float4*)(qp0 + 4);
    float4 q1a = *(const float4*)qp1, q1b = *(const float4*)(qp1 + 4);
    q0a.x *= SCL; q0a.y *= SCL; q0a.z *= SCL; q0a.w *= SCL;
    q0b.x *= SCL; q0b.y *= SCL; q0b.z *= SCL; q0b.w *= SCL;
    q1a.x *= SCL; q1a.y *= SCL; q1a.z *= SCL; q1a.w *= SCL;
    q1b.x *= SCL; q1b.y *= SCL; q1b.z *= SCL; q1b.w *= SCL;

    // ---- qw per (query, chunk column) from LDS ----
    float qw0[6], qw1[6];
#pragma unroll
    for (int c = 0; c < 6; ++c) {
        const int x2 = kc * 6 + c;
        const float* r0 = lrelw + (x2 - x0 + 47) * 8;
        const float* r1 = lrelw + (x2 - x1 + 47) * 8;
        float4 a0 = *(const float4*)r0, b0 = *(const float4*)(r0 + 4);
        float4 a1 = *(const float4*)r1, b1 = *(const float4*)(r1 + 4);
        qw0[c] = q0a.x*a0.x + q0a.y*a0.y + q0a.z*a0.z + q0a.w*a0.w
               + q0b.x*b0.x + q0b.y*b0.y + q0b.z*b0.z + q0b.w*b0.w;
        qw1[c] = q1a.x*a1.x + q1a.y*a1.y + q1a.z*a1.z + q1a.w*a1.w
               + q1b.x*b1.x + q1b.y*b1.y + q1b.z*b1.z + q1b.w*b1.w;
    }

    float l0 = 0.0f, l1 = 0.0f;
    float A0[8] = {0}, A1[8] = {0};

    // ---- lane -> staged key within a round (8 rows x 6 cols) ----
    int lr = lane / 6, lc = lane - lr * 6;
    if (lane >= 48) { lr = 7; lc = 5; }          // clamp (unused by readlane)
    const float* kvbase = in + ((size_t)(b * NQ + lr * 48 + kc * 6 + lc) * 192
                                + 64 + h * 8);
    const size_t RSTRIDE = (size_t)8 * 48 * 192;

    float4 ck0 = *(const float4*)kvbase;
    float4 ck1 = *(const float4*)(kvbase + 4);
    float4 cv0 = *(const float4*)(kvbase + 64);
    float4 cv1 = *(const float4*)(kvbase + 68);

#pragma unroll 1
    for (int R = 0; R < 6; ++R) {
        const float* np = kvbase + (size_t)(R < 5 ? R + 1 : 5) * RSTRIDE;
        float4 nk0 = *(const float4*)np;
        float4 nk1 = *(const float4*)(np + 4);
        float4 nv0 = *(const float4*)(np + 64);
        float4 nv1 = *(const float4*)(np + 68);

        // ---- batch-compute qh for this round's 8 rows (LDS, broadcast) ----
        float qh0[8], qh1[8];
#pragma unroll
        for (int row = 0; row < 8; ++row) {
            const int y2 = R * 8 + row;
            const float* r0 = lrelh + (y2 - y0 + 47) * 8;
            const float* r1 = lrelh + (y2 - y1 + 47) * 8;
            float4 a0 = *(const float4*)r0, b0 = *(const float4*)(r0 + 4);
            float4 a1 = *(const float4*)r1, b1 = *(const float4*)(r1 + 4);
            qh0[row] = q0a.x*a0.x + q0a.y*a0.y + q0a.z*a0.z + q0a.w*a0.w
                     + q0b.x*b0.x + q0b.y*b0.y + q0b.z*b0.z + q0b.w*b0.w - SHIFT;
            qh1[row] = q1a.x*a1.x + q1a.y*a1.y + q1a.z*a1.z + q1a.w*a1.w
                     + q1b.x*b1.x + q1b.y*b1.y + q1b.z*b1.z + q1b.w*b1.w - SHIFT;
        }

#pragma unroll 2
        for (int row = 0; row < 8; ++row) {
#pragma unroll
            for (int c = 0; c < 6; ++c) {
                const int idx = row * 6 + c;     // wave-uniform
                const float k0 = rdl(ck0.x, idx), k1 = rdl(ck0.y, idx);
                const float k2 = rdl(ck0.z, idx), k3 = rdl(ck0.w, idx);
                const float k4 = rdl(ck1.x, idx), k5 = rdl(ck1.y, idx);
                const float k6 = rdl(ck1.z, idx), k7 = rdl(ck1.w, idx);
                const float v0 = rdl(cv0.x, idx), v1 = rdl(cv0.y, idx);
                const float v2 = rdl(cv0.z, idx), v3 = rdl(cv0.w, idx);
                const float v4 = rdl(cv1.x, idx), v5 = rdl(cv1.y, idx);
                const float v6 = rdl(cv1.z, idx), v7 = rdl(cv1.w, idx);

                float dA0 = fmaf(q0a.x, k0, fmaf(q0a.y, k1,
                            fmaf(q0a.z, k2, q0a.w * k3)));
                float dB0 = fmaf(q0b.x, k4, fmaf(q0b.y, k5,
                            fmaf(q0b.z, k6, q0b.w * k7)));
                const float p0 = __builtin_amdgcn_exp2f(
                    (qh0[row] + qw0[c]) + (dA0 + dB0));
                l0 += p0;
                A0[0] = fmaf(p0, v0, A0[0]); A0[1] = fmaf(p0, v1, A0[1]);
                A0[2] = fmaf(p0, v2, A0[2]); A0[3] = fmaf(p0, v3, A0[3]);
                A0[4] = fmaf(p0, v4, A0[4]); A0[5] = fmaf(p0, v5, A0[5]);
                A0[6] = fmaf(p0, v6, A0[6]); A0[7] = fmaf(p0, v7, A0[7]);

                float dA1 = fmaf(q1a.x, k0, fmaf(q1a.y, k1,
                            fmaf(q1a.z, k2, q1a.w * k3)));
                float dB1 = fmaf(q1b.x, k4, fmaf(q1b.y, k5,
                            fmaf(q1b.z, k6, q1b.w * k7)));
                const float p1 = __builtin_amdgcn_exp2f(
                    (qh1[row] + qw1[c]) + (dA1 + dB1));
                l1 += p1;
                A1[0] = fmaf(p1, v0, A1[0]); A1[1] = fmaf(p1, v1, A1[1]);
                A1[2] = fmaf(p1, v2, A1[2]); A1[3] = fmaf(p1, v3, A1[3]);
                A1[4] = fmaf(p1, v4, A1[4]); A1[5] = fmaf(p1, v5, A1[5]);
                A1[6] = fmaf(p1, v6, A1[6]); A1[7] = fmaf(p1, v7, A1[7]);
            }
        }
        ck0 = nk0; ck1 = nk1; cv0 = nv0; cv1 = nv1;
    }

    // ---- store partial slab [9][256] for (kc, wt) ----
    float* pb = P + (size_t)(kc * NWT + wt) * PSLAB;
    const int q0i = wv * 128 + lane, q1i = q0i + 64;
    pb[q0i] = l0;
    pb[q1i] = l1;
#pragma unroll
    for (int e = 0; e < 8; ++e) {
        pb[(1 + e) * 256 + q0i] = A0[e];
        pb[(1 + e) * 256 + q1i] = A1[e];
    }

    // ---- last kc-block for this wt merges (device-scope handoff) ----
    __threadfence();
    __syncthreads();
    if (tid == 0) {
        __threadfence();
        sflag = (int)atomicAdd(&ctr[wt], 1u);
    }
    __syncthreads();
    if (sflag != 7) return;

    __threadfence();   // acquire: invalidate caches before reading peer slabs
    for (int qq = tid; qq < 256; qq += 128) {
        float s[9];
#pragma unroll
        for (int j = 0; j < 9; ++j) s[j] = 0.0f;
#pragma unroll
        for (int k2 = 0; k2 < 8; ++k2) {
            const float* ps = P + (size_t)(k2 * NWT + wt) * PSLAB;
#pragma unroll
            for (int j = 0; j < 9; ++j) s[j] += ps[j * 256 + qq];
        }
        const float inv = 1.0f / s[0];
        const int n = qt * 256 + qq;
        float* op = out + ((size_t)(b * NQ + n) * 64 + h * 8);
        ((float4*)op)[0] = make_float4(s[1]*inv, s[2]*inv, s[3]*inv, s[4]*inv);
        ((float4*)op)[1] = make_float4(s[5]*inv, s[6]*inv, s[7]*inv, s[8]*inv);
    }
}

extern "C" void kernel_launch(void* const* d_in, const int* in_sizes, int n_in,
                              void* d_out, int out_size, void* d_ws, size_t ws_size,
                              hipStream_t stream) {
    const float* in   = (const float*)d_in[0];
    const float* relw = (const float*)d_in[1];
    const float* relh = (const float*)d_in[2];
    float* P   = (float*)d_ws;                         // 10.6 MB partials
    unsigned int* ctr = (unsigned int*)((char*)d_ws + CTROFF);  // 144 counters
    float* out = (float*)d_out;

    hipMemsetAsync(ctr, 0, NWT * sizeof(unsigned int), stream);
    attn_fused<<<16 * 9 * 8, 128, 0, stream>>>(in, relw, relh, P, ctr, out);
}

// Round 10
// 152.685 us; speedup vs baseline: 1.8157x; 1.8157x over previous
//
#include <hip/hip_runtime.h>
#include <stdint.h>

#define WW 48
#define NQ 2304             // 48*48
#define NWT 144             // (bh, qt) tiles of 256 queries
#define NG 4                // kc groups (block merges 4 kc chunks)
#define SCL 0.51011868f     // 8^-0.5 * log2(e)  (folded so softmax = exp2)
#define SHIFT 17.312340491f // 12 * log2(e)      (fixed-shift softmax)
#define PSLAB 2304          // 9*256 floats per (g, wt) slab

// ---------------------------------------------------------------------------
// attn: 4 queries/lane, 4-wave blocks. 16-way key-column split (3 cols/chunk);
// wave w of a block handles kc = g*4 + w over the SAME 256-query tile.
// Each wave stages its own chunk (48 rows x 3 cols x 16 floats = 9.2 KB) into
// its private LDS quarter (no barrier: disjoint regions), then consumes keys
// via wave-uniform ds_read_b128 broadcast — the R5-verified delivery path
// (101us measured vs 104 modeled at 1 q/lane) amortized 4x by multi-q.
// qh batched per 8-row round from GLOBAL relh (L1-hot; R9's LDS rel reads
// were 16-way bank-conflicted). After the main loop the staging LDS is
// reused to merge the block's 4 kc partials -> P shrinks to 4 slabs (5.3 MB).
// logit = q.k + q.rel_w[x2-x+47] + q.rel_h[y2-y+47]; p = exp2(logit'-SHIFT)
// grid 576 = 16 bh * 9 qt * 4 g -> 2304 waves = 2.25/SIMD.
// ---------------------------------------------------------------------------
__global__ __launch_bounds__(256, 2) void attn_kernel(const float* __restrict__ in,
                                                      const float* __restrict__ relw,
                                                      const float* __restrict__ relh,
                                                      float* __restrict__ P) {
    __shared__ float4 lds[4][576];     // per-wave: staging chunk, later merge buf

    const int bx = blockIdx.x;
    const int bh = bx / 36;
    const int rem = bx - bh * 36;
    const int qt = rem >> 2;           // 0..8
    const int g = rem & 3;             // 0..3
    const int tid = threadIdx.x;
    const int lane = tid & 63;
    const int wv = tid >> 6;
    const int kc = g * 4 + wv;         // 0..15 (3 columns each)
    const int b = bh >> 3, h = bh & 7;
    const int wt = bh * 9 + qt;

    // ---- stage this wave's chunk: 48 rows x 3 cols, [k0..k7, v0..v7] ----
    // f4 index t: key = t>>2 (row*3+col), p = t&3 (K:0,1  V:2,3)
    const float4* inp4 = (const float4*)in;
    for (int t = lane; t < 576; t += 64) {
        const int key = t >> 2, p = t & 3;
        const int row = key / 3, col = key - row * 3;
        const size_t px = (size_t)(b * NQ + row * 48 + kc * 3 + col) * 48;
        const int c4 = (p < 2) ? (16 + h * 2 + p) : (32 + h * 2 + (p - 2));
        lds[wv][t] = inp4[px + c4];
    }

    // ---- this lane's four queries ----
    float4 qa[4], qb[4];
    int yq[4];
#pragma unroll
    for (int j = 0; j < 4; ++j) {
        const int n = qt * 256 + j * 64 + lane;
        const int y = n / WW;
        yq[j] = y;
        const int x = n - y * WW;
        const float* qp = in + ((size_t)(b * NQ + n) * 192 + h * 8);
        float4 a = *(const float4*)qp, bb = *(const float4*)(qp + 4);
        a.x *= SCL; a.y *= SCL; a.z *= SCL; a.w *= SCL;
        bb.x *= SCL; bb.y *= SCL; bb.z *= SCL; bb.w *= SCL;
        qa[j] = a; qb[j] = bb;
        (void)x;
    }

    // ---- qw per (query, chunk column) from global relw (once) ----
    float qw[4][3];
#pragma unroll
    for (int j = 0; j < 4; ++j) {
        const int n = qt * 256 + j * 64 + lane;
        const int x = n - yq[j] * WW;
#pragma unroll
        for (int c = 0; c < 3; ++c) {
            const float* rw = relw + (kc * 3 + c - x + 47) * 8;
            float4 ta = *(const float4*)rw, tb = *(const float4*)(rw + 4);
            qw[j][c] = qa[j].x*ta.x + qa[j].y*ta.y + qa[j].z*ta.z + qa[j].w*ta.w
                     + qb[j].x*tb.x + qb[j].y*tb.y + qb[j].z*tb.z + qb[j].w*tb.w;
        }
    }

    float l[4] = {0, 0, 0, 0};
    float A[4][8] = {{0}};

    const float* myl = (const float*)lds[wv];

#pragma unroll 1
    for (int R = 0; R < 6; ++R) {
        // ---- batch qh for this round's 8 rows (global relh, L1-hot) ----
        float qh[4][8];
#pragma unroll
        for (int row = 0; row < 8; ++row) {
            const int y2 = R * 8 + row;
#pragma unroll
            for (int j = 0; j < 4; ++j) {
                const float* rh = relh + (y2 - yq[j] + 47) * 8;
                float4 ta = *(const float4*)rh, tb = *(const float4*)(rh + 4);
                qh[j][row] =
                    qa[j].x*ta.x + qa[j].y*ta.y + qa[j].z*ta.z + qa[j].w*ta.w
                  + qb[j].x*tb.x + qb[j].y*tb.y + qb[j].z*tb.z + qb[j].w*tb.w
                  - SHIFT;
            }
        }

#pragma unroll 2
        for (int row = 0; row < 8; ++row) {
#pragma unroll
            for (int c = 0; c < 3; ++c) {
                const int base = ((R * 8 + row) * 3 + c) * 16;  // wave-uniform
                const float4 k0 = *(const float4*)(myl + base);
                const float4 k1 = *(const float4*)(myl + base + 4);
                const float4 v0 = *(const float4*)(myl + base + 8);
                const float4 v1 = *(const float4*)(myl + base + 12);
#pragma unroll
                for (int j = 0; j < 4; ++j) {
                    float dA = fmaf(qa[j].x, k0.x, fmaf(qa[j].y, k0.y,
                               fmaf(qa[j].z, k0.z, qa[j].w * k0.w)));
                    float dB = fmaf(qb[j].x, k1.x, fmaf(qb[j].y, k1.y,
                               fmaf(qb[j].z, k1.z, qb[j].w * k1.w)));
                    const float p = __builtin_amdgcn_exp2f(
                        (qh[j][row] + qw[j][c]) + (dA + dB));
                    l[j] += p;
                    A[j][0] = fmaf(p, v0.x, A[j][0]);
                    A[j][1] = fmaf(p, v0.y, A[j][1]);
                    A[j][2] = fmaf(p, v0.z, A[j][2]);
                    A[j][3] = fmaf(p, v0.w, A[j][3]);
                    A[j][4] = fmaf(p, v1.x, A[j][4]);
                    A[j][5] = fmaf(p, v1.y, A[j][5]);
                    A[j][6] = fmaf(p, v1.z, A[j][6]);
                    A[j][7] = fmaf(p, v1.w, A[j][7]);
                }
            }
        }
    }

    // ---- in-block merge of the 4 kc chunks (reuse staging LDS) ----
    __syncthreads();   // everyone done reading their staged KV
    float* mf = (float*)lds[wv];       // [9][256] floats per wave
#pragma unroll
    for (int j = 0; j < 4; ++j) {
        const int q = j * 64 + lane;
        mf[q] = l[j];
#pragma unroll
        for (int e = 0; e < 8; ++e) mf[(1 + e) * 256 + q] = A[j][e];
    }
    __syncthreads();

    const float* f0 = (const float*)lds[0];
    const float* f1 = (const float*)lds[1];
    const float* f2 = (const float*)lds[2];
    const float* f3 = (const float*)lds[3];
    float* pb = P + (size_t)(g * NWT + wt) * PSLAB;
    for (int idx = tid; idx < PSLAB; idx += 256)
        pb[idx] = (f0[idx] + f1[idx]) + (f2[idx] + f3[idx]);
}

// ---------------------------------------------------------------------------
// merge: sum 4 group-partials per query, normalize, write out[b][n][h*8+j]
// ---------------------------------------------------------------------------
__global__ __launch_bounds__(256) void merge_kernel(const float* __restrict__ P,
                                                    float* __restrict__ out) {
    const int t = blockIdx.x * 256 + threadIdx.x;   // [0, 36864)
    const int wt = t >> 8, q = t & 255;
    float s[9];
#pragma unroll
    for (int j = 0; j < 9; ++j) s[j] = 0.0f;
#pragma unroll
    for (int g = 0; g < NG; ++g) {
        const float* pb = P + (size_t)(g * NWT + wt) * PSLAB;
#pragma unroll
        for (int j = 0; j < 9; ++j) s[j] += pb[j * 256 + q];
    }
    const float inv = 1.0f / s[0];
    const int bh = wt / 9;
    const int qtl = wt - bh * 9;
    const int n = qtl * 256 + q;
    const int b = bh >> 3, h = bh & 7;
    float* op = out + ((size_t)(b * NQ + n) * 64 + h * 8);
    ((float4*)op)[0] = make_float4(s[1]*inv, s[2]*inv, s[3]*inv, s[4]*inv);
    ((float4*)op)[1] = make_float4(s[5]*inv, s[6]*inv, s[7]*inv, s[8]*inv);
}

extern "C" void kernel_launch(void* const* d_in, const int* in_sizes, int n_in,
                              void* d_out, int out_size, void* d_ws, size_t ws_size,
                              hipStream_t stream) {
    const float* in   = (const float*)d_in[0];
    const float* relw = (const float*)d_in[1];
    const float* relh = (const float*)d_in[2];
    float* P   = (float*)d_ws;    // 4 * 144 * 2304 * 4 B = 5.3 MB (fits proven ws)
    float* out = (float*)d_out;

    attn_kernel<<<16 * 9 * 4, 256, 0, stream>>>(in, relw, relh, P);
    merge_kernel<<<144, 256, 0, stream>>>(P, out);
}